// Round 6
// baseline (311.021 us; speedup 1.0000x reference)
//
#include <hip/hip_runtime.h>
#include <math.h>

#define N_NODES 25000
#define N_EDGES 400000
#define FEAT 128
#define HID 64
#define HEADS 4
#define HH 256   // HEADS*HID
#define NUM_GRAPHS 64
#define BUCKET 96     // max in-degree slots (mean 16, sigma 4 -> P(>96)~1e-80)
#define HS 1601536    // head-major slice stride in ushorts = 25024*64
#define NPH 25600     // head-major stride for a_s/a_d (floats)
#define FILL_BLOCKS 1563   // ceil(N_EDGES/256); 1563%8==3 -> conv1 XCD offset

typedef unsigned short ushort_t;
typedef unsigned int uint_t;
typedef __attribute__((ext_vector_type(8))) short short8;   // 8 bf16 (4 VGPRs)
typedef __attribute__((ext_vector_type(4))) float f32x4;

__device__ __forceinline__ float lrelu(float x){ return x > 0.f ? x : 0.2f*x; }

// fp32 -> bf16 with round-to-nearest-even
__device__ __forceinline__ ushort_t f2bf(float f){
  uint_t u = __float_as_uint(f);
  return (ushort_t)((u + 0x7fffu + ((u >> 16) & 1u)) >> 16);
}
#define BF_LO(u) __uint_as_float((u) << 16)
#define BF_HI(u) __uint_as_float((u) & 0xffff0000u)

// ====== init: zero g+cnt+slot-prefix, pack all MFMA weight fragments ========
__global__ __launch_bounds__(256) void k_init(
    const float* __restrict__ W1_rel, const float* __restrict__ W1_root,
    const float* __restrict__ W5_rel, const float* __restrict__ W5_root,
    const float* __restrict__ Wg,
    ushort_t* __restrict__ wc1b, ushort_t* __restrict__ wc5b,
    ushort_t* __restrict__ wgb, float* __restrict__ g /* g|cnt contiguous */,
    ushort_t* __restrict__ slot)
{
  const int e = blockIdx.x*256 + threadIdx.x;   // 64 blocks -> e in [0,16384)
  { // conv1 [Wrel|Wroot] 128x128: nt<8, kc<4
    int j=e&7, lane=(e>>3)&63, kc=(e>>9)&3, nt=e>>11;
    int k = kc*32 + (lane>>4)*8 + j, n = nt*16 + (lane&15);
    float v = (n < 64) ? W1_rel[k*64 + n] : W1_root[k*64 + n - 64];
    wc1b[e] = f2bf(v);
  }
  { // Wg 64x256: nt<16, kt<2
    int j=e&7, lane=(e>>3)&63, kt=(e>>9)&1, nt=e>>10;
    int k = kt*32 + (lane>>4)*8 + j, n = nt*16 + (lane&15);
    wgb[e] = f2bf(Wg[k*HH + n]);
  }
  #pragma unroll
  for (int e5 = e; e5 < 32768; e5 += 16384){ // conv5 256x128: nt<8, kc<8
    int j=e5&7, lane=(e5>>3)&63, kc=(e5>>9)&7, nt=e5>>12;
    int k = kc*32 + (lane>>4)*8 + j, n = nt*16 + (lane&15);
    float v = (n < 64) ? W5_rel[k*64 + n] : W5_root[k*64 + n - 64];
    wc5b[e5] = f2bf(v);
  }
  // zero g (4096 f32) + cnt (25000 int), laid out contiguously after g
  int* z = (int*)g;
  for (int i = e; i < 4096 + N_NODES; i += 16384) z[i] = 0;
  // zero first 32 slots of every row (safety net: k_aggb's index-pack load
  // reads them; gathers are deg-predicated so junk is never dereferenced,
  // but zeroing keeps any compiler-speculated access benign).
  const uint4 zz = {0,0,0,0};
  for (int n = e; n < N_NODES; n += 16384){
    uint4* p = (uint4*)(slot + (size_t)n*BUCKET);   // row = 192B, 16B-aligned
    p[0] = zz; p[1] = zz; p[2] = zz; p[3] = zz;     // first 64B = 32 ushorts
  }
}

// ====== fused: CSR bucket scatter (blocks [0,FILL_BLOCKS)) + conv1 MFMA ======
// conv1 cluster cb (nodes [64cb,64cb+64)) runs on XCD (cb+3)%8 (blockIdx
// offset 1563 ≡ 3 mod 8) -> its xr/root writes are dirty in that XCD's L2.
__global__ __launch_bounds__(256) void k_c1_fill(
    const int* __restrict__ src, const int* __restrict__ dst,
    int* __restrict__ cnt, ushort_t* __restrict__ slot,
    const float* __restrict__ X, const ushort_t* __restrict__ wc1b,
    const float* __restrict__ bias,
    ushort_t* __restrict__ out_rel_b, ushort_t* __restrict__ out_root_b)
{
  if (blockIdx.x < FILL_BLOCKS){
    const int e = blockIdx.x*256 + threadIdx.x;
    if (e < N_EDGES){
      int d = dst[e];
      int pos = atomicAdd(&cnt[d], 1);
      if (pos < BUCKET) slot[(size_t)d*BUCKET + pos] = (ushort_t)src[e];
    }
    return;
  }
  // conv1: [rel|root] = x @ [Wrel|Wroot], K=128, M=128
  const int wid  = __builtin_amdgcn_readfirstlane(threadIdx.x >> 6);
  const int lane = threadIdx.x & 63;
  const int quad = lane >> 4, col = lane & 15;
  const int nb = (blockIdx.x - FILL_BLOCKS)*64 + wid*16;
  if (nb >= N_NODES) return;
  const int row = min(nb + col, N_NODES-1);
  const float* __restrict__ xr = X + (size_t)row*FEAT + quad*8;
  short8 a[4];
  #pragma unroll
  for (int kc = 0; kc < 4; kc++){
    #pragma unroll
    for (int j = 0; j < 8; j++)
      ((ushort_t*)&a[kc])[j] = f2bf(xr[kc*32 + j]);
  }
  #pragma unroll
  for (int nt = 0; nt < 8; nt++){
    f32x4 d = {0.f,0.f,0.f,0.f};
    #pragma unroll
    for (int kc = 0; kc < 4; kc++){
      short8 b = *(const short8*)(wc1b + ((size_t)(nt*4+kc)*64 + lane)*8);
      d = __builtin_amdgcn_mfma_f32_16x16x32_bf16(a[kc], b, d, 0, 0, 0);
    }
    if (nt < 4){
      #pragma unroll
      for (int r = 0; r < 4; r++){
        const int node = nb + quad*4 + r;
        if (node < N_NODES)
          out_rel_b[(size_t)node*HID + nt*16 + col] = f2bf(d[r]);
      }
    } else {
      const float bv = bias[(nt-4)*16 + col];
      #pragma unroll
      for (int r = 0; r < 4; r++){
        const int node = nb + quad*4 + r;
        if (node < N_NODES)
          out_root_b[(size_t)node*HID + (nt-4)*16 + col] = f2bf(d[r] + bv);
      }
    }
  }
}

// ====== conv5 via MFMA: A from HEAD-MAJOR h2b ================================
// cluster cb on XCD cb%8 (default mapping) -> k_aggb<1> uses OFF=0.
__global__ __launch_bounds__(256) void conv5_mfma(
    const ushort_t* __restrict__ h2b_hm, const ushort_t* __restrict__ wc5b,
    const float* __restrict__ bias,
    ushort_t* __restrict__ out_rel_b, ushort_t* __restrict__ out_root_b)
{
  const int wid  = __builtin_amdgcn_readfirstlane(threadIdx.x >> 6);
  const int lane = threadIdx.x & 63;
  const int quad = lane >> 4, col = lane & 15;
  const int nb = blockIdx.x*64 + wid*16;
  if (nb >= N_NODES) return;
  const int row = nb + col;                    // < 25024 (padded slices)
  short8 a[8];
  #pragma unroll
  for (int kc = 0; kc < 8; kc++){
    const int k0 = kc*32 + quad*8;             // 8-chunk never crosses a head
    a[kc] = *(const short8*)(h2b_hm + (size_t)(k0>>6)*HS
                             + (size_t)row*HID + (k0&63));
  }
  #pragma unroll
  for (int nt = 0; nt < 8; nt++){
    f32x4 d = {0.f,0.f,0.f,0.f};
    #pragma unroll
    for (int kc = 0; kc < 8; kc++){
      short8 b = *(const short8*)(wc5b + ((size_t)(nt*8+kc)*64 + lane)*8);
      d = __builtin_amdgcn_mfma_f32_16x16x32_bf16(a[kc], b, d, 0, 0, 0);
    }
    if (nt < 4){
      #pragma unroll
      for (int r = 0; r < 4; r++){
        const int node = nb + quad*4 + r;
        if (node < N_NODES)
          out_rel_b[(size_t)node*HID + nt*16 + col] = f2bf(d[r]);
      }
    } else {
      const float bv = bias[(nt-4)*16 + col];
      #pragma unroll
      for (int r = 0; r < 4; r++){
        const int node = nb + quad*4 + r;
        if (node < N_NODES)
          out_root_b[(size_t)node*HID + (nt-4)*16 + col] = f2bf(d[r] + bv);
      }
    }
  }
}

// ====== GAT transform via MFMA -> HEAD-MAJOR xl, a_s, a_d ====================
// XCD-swizzled: block on XCD j handles cluster cb with (cb+3)%8==j, so its
// h1b reads hit the L2 where k_aggb<0> (OFF=5) wrote them.
__global__ __launch_bounds__(256) void k3_mfma(
    const ushort_t* __restrict__ h1b, const ushort_t* __restrict__ wgb,
    const float* __restrict__ att_src, const float* __restrict__ att_dst,
    ushort_t* __restrict__ xlb_hm, float* __restrict__ a_s_hm,
    float* __restrict__ a_d_hm)
{
  const int jx = blockIdx.x & 7;
  const int cb = (blockIdx.x >> 3)*8 + ((jx + 5) & 7);
  if (cb > (N_NODES + 63)/64 - 1 + 1) return;  // cb==391 -> no real nodes
  if (cb*64 >= N_NODES + 24) return;           // guard padded tail cluster
  const int wid  = __builtin_amdgcn_readfirstlane(threadIdx.x >> 6);
  const int lane = threadIdx.x & 63;
  const int quad = lane >> 4, col = lane & 15;
  const int nb = cb*64 + wid*16;
  const ushort_t* arow = h1b + (size_t)(nb + col)*HID + quad*8;
  short8 a0 = *(const short8*)(arow);
  short8 a1 = *(const short8*)(arow + 32);
  float as_acc[4] = {0,0,0,0}, ad_acc[4] = {0,0,0,0};
  #pragma unroll
  for (int nt = 0; nt < 16; nt++){
    short8 b0 = *(const short8*)(wgb + ((size_t)(nt*2+0)*64 + lane)*8);
    short8 b1 = *(const short8*)(wgb + ((size_t)(nt*2+1)*64 + lane)*8);
    f32x4 d = {0.f, 0.f, 0.f, 0.f};
    d = __builtin_amdgcn_mfma_f32_16x16x32_bf16(a0, b0, d, 0, 0, 0);
    d = __builtin_amdgcn_mfma_f32_16x16x32_bf16(a1, b1, d, 0, 0, 0);
    const int h = nt >> 2;
    const float asv = att_src[h*HID + (nt & 3)*16 + col];
    const float adv = att_dst[h*HID + (nt & 3)*16 + col];
    #pragma unroll
    for (int r = 0; r < 4; r++){
      const int node = nb + quad*4 + r;
      if (node < N_NODES)
        xlb_hm[(size_t)h*HS + (size_t)node*HID + (nt&3)*16 + col] = f2bf(d[r]);
      as_acc[r] += d[r]*asv;
      ad_acc[r] += d[r]*adv;
    }
    if ((nt & 3) == 3){                        // finish head h
      #pragma unroll
      for (int r = 0; r < 4; r++){
        float s1 = as_acc[r], s2 = ad_acc[r];
        #pragma unroll
        for (int off = 1; off < 16; off <<= 1){
          s1 += __shfl_xor(s1, off, 64);
          s2 += __shfl_xor(s2, off, 64);
        }
        const int node = nb + quad*4 + r;
        if (col == 0 && node < N_NODES){
          a_s_hm[h*NPH + node] = s1;
          a_d_hm[h*NPH + node] = s2;
        }
        as_acc[r] = 0.f; ad_acc[r] = 0.f;
      }
    }
  }
}

// -------- gather agg v6: block=node, deg-predicated gathers, XCD affinity ----
// Block on XCD j (=blockIdx%8) processes node in producer cluster c with
// writer-XCD == j (OFF=5 matches k_c1_fill's +3 offset; OFF=0 matches conv5's
// default mapping) -> root read and h1 write are L2-local.
// Gathers predicated on (w*8+j < deg): wave-uniform -> exec-mask all-or-none
// -> skipped loads issue no fabric traffic (mean deg=16 halves gather volume
// vs unconditional 32).
// MODE 0: write relu'd row as bf16. MODE 1: fused global_add_pool atomics.
template<int MODE, int OFF>
__global__ __launch_bounds__(256, 8) void k_aggb(
    const int* __restrict__ cnt, const ushort_t* __restrict__ slot,
    const ushort_t* __restrict__ featb, const ushort_t* __restrict__ rootb,
    const int* __restrict__ batch, float* __restrict__ g,
    ushort_t* __restrict__ outb)
{
  __shared__ float red[3*HID];
  const int jx = blockIdx.x & 7;               // XCD id (round-robin)
  const int i  = blockIdx.x >> 3;              // [0, 3136)
  const int c  = (i >> 6)*8 + ((jx + OFF) & 7);// producer 64-node cluster
  const int node = c*64 + (i & 63);
  if (node >= N_NODES) return;
  const int w    = threadIdx.x >> 6;
  const int lane = threadIdx.x & 63;
  const ushort_t* __restrict__ sl = slot + (size_t)node*BUCKET;
  // static-address loads -> issue immediately, all independent
  const int4 pk = ((const int4*)sl)[w];        // 8 u16 indices for this wave
  uint_t rt = 0;
  if (w == 0) rt = rootb[(size_t)node*HID + lane];
  const int deg = min(cnt[node], BUCKET);
  const uint_t pw[4] = {(uint_t)pk.x, (uint_t)pk.y, (uint_t)pk.z, (uint_t)pk.w};
  float acc = 0.f;
  #pragma unroll
  for (int j = 0; j < 8; j++){
    uint_t u = 0u;
    const uint_t s = (j & 1) ? (pw[j>>1] >> 16) : (pw[j>>1] & 0xffffu);
    if (w*8 + j < deg)                         // wave-uniform -> whole-wave skip
      u = featb[(size_t)s*HID + lane];
    acc += BF_LO(u);
  }
  if (w == 3)
    for (int t = 32; t < deg; t++)             // astronomically rare tail
      acc += BF_LO((uint_t)featb[(size_t)sl[t]*HID + lane]);
  if (w) red[(w-1)*HID + lane] = acc;
  __syncthreads();
  if (w == 0){
    acc += red[lane] + red[HID + lane] + red[2*HID + lane];
    acc += BF_LO(rt);
    const float v = fmaxf(acc, 0.f);
    if (MODE == 0){
      outb[(size_t)node*HID + lane] = f2bf(v);
    } else {
      const int b = batch[node];               // wave-uniform
      atomicAdd(&g[b*HID + lane], v);
    }
  }
}

// ---- GAT softmax+aggregate v6: head-per-block, 16-lane group = 1 node -------
__global__ __launch_bounds__(256) void k_gat_node(
    const int* __restrict__ cnt, const ushort_t* __restrict__ slot,
    const ushort_t* __restrict__ xlb_hm, const float* __restrict__ a_s_hm,
    const float* __restrict__ a_d_hm, const float* __restrict__ bg,
    ushort_t* __restrict__ h2b_hm)
{
  const int head = blockIdx.x & 3;
  const int node = (blockIdx.x >> 2)*16 + (threadIdx.x >> 4);
  if (node >= N_NODES) return;                 // whole 16-lane group exits
  const int lane = threadIdx.x & 63;
  const int cl = lane & 15;
  const int gb = lane & 48;                    // group base within wave
  const ushort_t* __restrict__ sl = slot + (size_t)node*BUCKET;
  const int deg = min(cnt[node], BUCKET);
  const ushort_t* __restrict__ xlh = xlb_hm + (size_t)head*HS;
  const float* __restrict__ ash = a_s_hm + head*NPH;
  const float adh = a_d_hm[head*NPH + node];
  float acc0=0, acc1=0, acc2=0, acc3=0;
  float dsum = 0.f;
  for (int base = 0; base < deg; base += 16){
    // phase 1: lane cl owns edge base+cl -> exp once per (edge,head)
    float pme = 0.f; int sme = node;
    const int e = base + cl;
    if (e < deg){
      sme = sl[e];
      pme = __expf(lrelu(ash[sme] + adh));
    }
    dsum += pme;
    // phase 2: stream the chunk's edges through the 16-lane group, unroll x2
    const int nsub = min(16, deg - base);
    int s = 0;
    for (; s + 2 <= nsub; s += 2){
      const float pA = __shfl(pme, gb + s, 64);
      const int   sA = __shfl(sme, gb + s, 64);
      const float pB = __shfl(pme, gb + s + 1, 64);
      const int   sB = __shfl(sme, gb + s + 1, 64);
      uint2 rA = ((const uint2*)(xlh + (size_t)sA*HID))[cl];
      uint2 rB = ((const uint2*)(xlh + (size_t)sB*HID))[cl];
      acc0 += pA*BF_LO(rA.x); acc1 += pA*BF_HI(rA.x);
      acc2 += pA*BF_LO(rA.y); acc3 += pA*BF_HI(rA.y);
      acc0 += pB*BF_LO(rB.x); acc1 += pB*BF_HI(rB.x);
      acc2 += pB*BF_LO(rB.y); acc3 += pB*BF_HI(rB.y);
    }
    if (s < nsub){
      const float pA = __shfl(pme, gb + s, 64);
      const int   sA = __shfl(sme, gb + s, 64);
      uint2 rA = ((const uint2*)(xlh + (size_t)sA*HID))[cl];
      acc0 += pA*BF_LO(rA.x); acc1 += pA*BF_HI(rA.x);
      acc2 += pA*BF_LO(rA.y); acc3 += pA*BF_HI(rA.y);
    }
  }
  // denom reduce within the 16-lane group
  #pragma unroll
  for (int off = 1; off < 16; off <<= 1) dsum += __shfl_xor(dsum, off, 64);
  // self loop + epilogue (all 16 lanes write their cols)
  const float pself = __expf(lrelu(ash[node] + adh));
  const float inv = 1.f / (dsum + pself);
  uint2 r = ((const uint2*)(xlh + (size_t)node*HID))[cl];
  acc0 += pself*BF_LO(r.x); acc1 += pself*BF_HI(r.x);
  acc2 += pself*BF_LO(r.y); acc3 += pself*BF_HI(r.y);
  const int col0 = head*HID + cl*4;
  const float ox = fmaxf(acc0*inv + bg[col0+0], 0.f);
  const float oy = fmaxf(acc1*inv + bg[col0+1], 0.f);
  const float oz = fmaxf(acc2*inv + bg[col0+2], 0.f);
  const float ow = fmaxf(acc3*inv + bg[col0+3], 0.f);
  uint2 o;
  o.x = (uint_t)f2bf(ox) | ((uint_t)f2bf(oy) << 16);
  o.y = (uint_t)f2bf(oz) | ((uint_t)f2bf(ow) << 16);
  ((uint2*)(h2b_hm + (size_t)head*HS + (size_t)node*HID))[cl] = o;
}

__global__ __launch_bounds__(256) void k_head(
    const float* __restrict__ g, const float* __restrict__ W1,
    const float* __restrict__ b1, const float* __restrict__ W2,
    const float* __restrict__ b2, float* __restrict__ out)
{
  __shared__ float gs[NUM_GRAPHS*HID];
  __shared__ float hh[NUM_GRAPHS*HID];
  for (int i = threadIdx.x; i < NUM_GRAPHS*HID; i += 256) gs[i] = g[i];
  __syncthreads();
  for (int t = threadIdx.x; t < NUM_GRAPHS*HID; t += 256){
    int b = t >> 6, j = t & 63;
    float acc = b1[j];
    for (int k = 0; k < HID; k++) acc += gs[b*HID+k]*W1[k*HID+j];
    hh[t] = fmaxf(acc, 0.f);
  }
  __syncthreads();
  for (int t = threadIdx.x; t < NUM_GRAPHS*2; t += 256){
    int b = t >> 1, c = t & 1;
    float acc = b2[c];
    for (int k = 0; k < HID; k++) acc += hh[b*HID+k]*W2[k*2+c];
    out[t] = 1.f / (1.f + __expf(-acc));
  }
}

extern "C" void kernel_launch(void* const* d_in, const int* in_sizes, int n_in,
                              void* d_out, int out_size, void* d_ws, size_t ws_size,
                              hipStream_t stream)
{
  const float* x       = (const float*)d_in[0];
  const int*   ei      = (const int*)d_in[1];
  const int*   batch   = (const int*)d_in[2];
  const float* W1_rel  = (const float*)d_in[3];
  const float* b1      = (const float*)d_in[4];
  const float* W1_root = (const float*)d_in[5];
  const float* Wg      = (const float*)d_in[6];
  const float* att_src = (const float*)d_in[7];
  const float* att_dst = (const float*)d_in[8];
  const float* bg      = (const float*)d_in[9];
  const float* W5_rel  = (const float*)d_in[10];
  const float* b5      = (const float*)d_in[11];
  const float* W5_root = (const float*)d_in[12];
  const float* W_fc1   = (const float*)d_in[13];
  const float* b_fc1   = (const float*)d_in[14];
  const float* W_fc2   = (const float*)d_in[15];
  const float* b_fc2   = (const float*)d_in[16];
  const int* src = ei;
  const int* dst = ei + N_EDGES;

  // ---- workspace layout, FLOAT (4-byte) units (bf16 count = 2x fu) ---------
  float* ws    = (float*)d_ws;
  ushort_t* xr_b   = (ushort_t*)ws;             // rel bf16  [0, 800800)
  ushort_t* rootb  = (ushort_t*)(ws + 800800);  // root bf16
  ushort_t* h1b    = (ushort_t*)(ws + 2402400); // [2402400,  3203200)
  ushort_t* xlb_hm = (ushort_t*)(ws + 3203200); // [3203200,  6406304)
  float*    a_s_hm = ws + 6406304;              // [6406304,  6508704)
  float*    a_d_hm = ws + 6508704;              // [6508704,  6611104)
  ushort_t* h2b_hm = (ushort_t*)(ws + 6611104); // [6611104,  9814200)
  float*    g      = ws + 9814200;              // [9814200,  9818296)
  int*      cnt    = (int*)(ws + 9818296);      // [9818296,  9843296)  (g|cnt contiguous)
  ushort_t* wc1b   = (ushort_t*)(ws + 9843296); // [9843296,  9851488)
  ushort_t* wc5b   = (ushort_t*)(ws + 9851488); // [9851488,  9867872)
  ushort_t* wgb    = (ushort_t*)(ws + 9867872); // [9867872,  9876064)
  ushort_t* slot   = (ushort_t*)(ws + 9876064); // ushort slots
  float*    out    = (float*)d_out;

  // init: zero g+cnt+slot-prefix + pack all weights
  k_init<<<64,256,0,stream>>>(W1_rel, W1_root, W5_rel, W5_root, Wg,
                              wc1b, wc5b, wgb, g, slot);

  // fused CSR scatter + conv1 MFMA (independent halves, one dispatch)
  k_c1_fill<<<FILL_BLOCKS + (N_NODES+63)/64,256,0,stream>>>(
      src, dst, cnt, slot, x, wc1b, b1, xr_b, rootb);

  // agg -> h1 bf16 (block=node, XCD-affine to k_c1_fill's conv1 writes)
  k_aggb<0,5><<<25088,256,0,stream>>>(cnt, slot, xr_b, rootb,
                                      nullptr, nullptr, h1b);

  // GAT: MFMA transform (XCD-affine to k_aggb<0> h1 writes) + softmax-agg
  k3_mfma<<<392,256,0,stream>>>(h1b, wgb, att_src, att_dst,
                                xlb_hm, a_s_hm, a_d_hm);
  k_gat_node<<<((N_NODES+15)/16)*HEADS,256,0,stream>>>(cnt, slot,
      xlb_hm, a_s_hm, a_d_hm, bg, h2b_hm);

  // conv5 (MFMA, head-major A) + agg fused with global_add_pool
  conv5_mfma<<<(N_NODES+63)/64,256,0,stream>>>(h2b_hm, wc5b, b5, xr_b, rootb);
  k_aggb<1,0><<<25088,256,0,stream>>>(cnt, slot, xr_b, rootb,
                                      batch, g, nullptr);

  // head
  k_head<<<1,256,0,stream>>>(g, W_fc1, b_fc1, W_fc2, b_fc2, out);
}

// Round 7
// 262.032 us; speedup vs baseline: 1.1870x; 1.1870x over previous
//
#include <hip/hip_runtime.h>
#include <math.h>

#define N_NODES 25000
#define N_EDGES 400000
#define FEAT 128
#define HID 64
#define HEADS 4
#define HH 256   // HEADS*HID
#define NUM_GRAPHS 64
#define BUCKET 96     // max in-degree slots (mean 16, sigma 4 -> P(>96)~1e-80)
#define HS 1601536    // head-major slice stride in ushorts = 25024*64
#define NPH 25600     // head-major stride for a_s/a_d (floats)
#define FILL_BLOCKS 1563   // ceil(N_EDGES/256)

typedef unsigned short ushort_t;
typedef unsigned int uint_t;
typedef __attribute__((ext_vector_type(8))) short short8;   // 8 bf16 (4 VGPRs)
typedef __attribute__((ext_vector_type(4))) float f32x4;

__device__ __forceinline__ float lrelu(float x){ return x > 0.f ? x : 0.2f*x; }

// fp32 -> bf16 with round-to-nearest-even
__device__ __forceinline__ ushort_t f2bf(float f){
  uint_t u = __float_as_uint(f);
  return (ushort_t)((u + 0x7fffu + ((u >> 16) & 1u)) >> 16);
}
#define BF_LO(u) __uint_as_float((u) << 16)
#define BF_HI(u) __uint_as_float((u) & 0xffff0000u)

// ====== init: zero g+cnt+slot-prefix, pack all MFMA weight fragments ========
__global__ __launch_bounds__(256) void k_init(
    const float* __restrict__ W1_rel, const float* __restrict__ W1_root,
    const float* __restrict__ W5_rel, const float* __restrict__ W5_root,
    const float* __restrict__ Wg,
    ushort_t* __restrict__ wc1b, ushort_t* __restrict__ wc5b,
    ushort_t* __restrict__ wgb, float* __restrict__ g /* g|cnt contiguous */,
    ushort_t* __restrict__ slot)
{
  const int e = blockIdx.x*256 + threadIdx.x;   // 64 blocks -> e in [0,16384)
  { // conv1 [Wrel|Wroot] 128x128: nt<8, kc<4
    int j=e&7, lane=(e>>3)&63, kc=(e>>9)&3, nt=e>>11;
    int k = kc*32 + (lane>>4)*8 + j, n = nt*16 + (lane&15);
    float v = (n < 64) ? W1_rel[k*64 + n] : W1_root[k*64 + n - 64];
    wc1b[e] = f2bf(v);
  }
  { // Wg 64x256: nt<16, kt<2
    int j=e&7, lane=(e>>3)&63, kt=(e>>9)&1, nt=e>>10;
    int k = kt*32 + (lane>>4)*8 + j, n = nt*16 + (lane&15);
    wgb[e] = f2bf(Wg[k*HH + n]);
  }
  #pragma unroll
  for (int e5 = e; e5 < 32768; e5 += 16384){ // conv5 256x128: nt<8, kc<8
    int j=e5&7, lane=(e5>>3)&63, kc=(e5>>9)&7, nt=e5>>12;
    int k = kc*32 + (lane>>4)*8 + j, n = nt*16 + (lane&15);
    float v = (n < 64) ? W5_rel[k*64 + n] : W5_root[k*64 + n - 64];
    wc5b[e5] = f2bf(v);
  }
  // zero g (4096 f32) + cnt (25000 int), laid out contiguously after g
  int* z = (int*)g;
  for (int i = e; i < 4096 + N_NODES; i += 16384) z[i] = 0;
  // zero first 32 slots of every row: k_aggb gathers those 32 indices
  // UNCONDITIONALLY; zeroed junk -> node 0's cache-hot row (safe + free-ish).
  const uint4 zz = {0,0,0,0};
  for (int n = e; n < N_NODES; n += 16384){
    uint4* p = (uint4*)(slot + (size_t)n*BUCKET);   // row = 192B, 16B-aligned
    p[0] = zz; p[1] = zz; p[2] = zz; p[3] = zz;     // first 64B = 32 ushorts
  }
}

// ====== fused: CSR bucket scatter (blocks [0,FILL_BLOCKS)) + conv1 MFMA ======
__global__ __launch_bounds__(256) void k_c1_fill(
    const int* __restrict__ src, const int* __restrict__ dst,
    int* __restrict__ cnt, ushort_t* __restrict__ slot,
    const float* __restrict__ X, const ushort_t* __restrict__ wc1b,
    const float* __restrict__ bias,
    ushort_t* __restrict__ out_rel_b, ushort_t* __restrict__ out_root_b)
{
  if (blockIdx.x < FILL_BLOCKS){
    const int e = blockIdx.x*256 + threadIdx.x;
    if (e < N_EDGES){
      int d = dst[e];
      int pos = atomicAdd(&cnt[d], 1);
      if (pos < BUCKET) slot[(size_t)d*BUCKET + pos] = (ushort_t)src[e];
    }
    return;
  }
  // conv1: [rel|root] = x @ [Wrel|Wroot], K=128, M=128
  const int wid  = __builtin_amdgcn_readfirstlane(threadIdx.x >> 6);
  const int lane = threadIdx.x & 63;
  const int quad = lane >> 4, col = lane & 15;
  const int nb = (blockIdx.x - FILL_BLOCKS)*64 + wid*16;
  if (nb >= N_NODES) return;
  const int row = min(nb + col, N_NODES-1);
  const float* __restrict__ xr = X + (size_t)row*FEAT + quad*8;
  short8 a[4];
  #pragma unroll
  for (int kc = 0; kc < 4; kc++){
    #pragma unroll
    for (int j = 0; j < 8; j++)
      ((ushort_t*)&a[kc])[j] = f2bf(xr[kc*32 + j]);
  }
  #pragma unroll
  for (int nt = 0; nt < 8; nt++){
    f32x4 d = {0.f,0.f,0.f,0.f};
    #pragma unroll
    for (int kc = 0; kc < 4; kc++){
      short8 b = *(const short8*)(wc1b + ((size_t)(nt*4+kc)*64 + lane)*8);
      d = __builtin_amdgcn_mfma_f32_16x16x32_bf16(a[kc], b, d, 0, 0, 0);
    }
    if (nt < 4){
      #pragma unroll
      for (int r = 0; r < 4; r++){
        const int node = nb + quad*4 + r;
        if (node < N_NODES)
          out_rel_b[(size_t)node*HID + nt*16 + col] = f2bf(d[r]);
      }
    } else {
      const float bv = bias[(nt-4)*16 + col];
      #pragma unroll
      for (int r = 0; r < 4; r++){
        const int node = nb + quad*4 + r;
        if (node < N_NODES)
          out_root_b[(size_t)node*HID + (nt-4)*16 + col] = f2bf(d[r] + bv);
      }
    }
  }
}

// ====== conv5 via MFMA: A from HEAD-MAJOR h2b ================================
__global__ __launch_bounds__(256) void conv5_mfma(
    const ushort_t* __restrict__ h2b_hm, const ushort_t* __restrict__ wc5b,
    const float* __restrict__ bias,
    ushort_t* __restrict__ out_rel_b, ushort_t* __restrict__ out_root_b)
{
  const int wid  = __builtin_amdgcn_readfirstlane(threadIdx.x >> 6);
  const int lane = threadIdx.x & 63;
  const int quad = lane >> 4, col = lane & 15;
  const int nb = blockIdx.x*64 + wid*16;
  if (nb >= N_NODES) return;
  const int row = nb + col;                    // < 25024 (padded slices)
  short8 a[8];
  #pragma unroll
  for (int kc = 0; kc < 8; kc++){
    const int k0 = kc*32 + quad*8;             // 8-chunk never crosses a head
    a[kc] = *(const short8*)(h2b_hm + (size_t)(k0>>6)*HS
                             + (size_t)row*HID + (k0&63));
  }
  #pragma unroll
  for (int nt = 0; nt < 8; nt++){
    f32x4 d = {0.f,0.f,0.f,0.f};
    #pragma unroll
    for (int kc = 0; kc < 8; kc++){
      short8 b = *(const short8*)(wc5b + ((size_t)(nt*8+kc)*64 + lane)*8);
      d = __builtin_amdgcn_mfma_f32_16x16x32_bf16(a[kc], b, d, 0, 0, 0);
    }
    if (nt < 4){
      #pragma unroll
      for (int r = 0; r < 4; r++){
        const int node = nb + quad*4 + r;
        if (node < N_NODES)
          out_rel_b[(size_t)node*HID + nt*16 + col] = f2bf(d[r]);
      }
    } else {
      const float bv = bias[(nt-4)*16 + col];
      #pragma unroll
      for (int r = 0; r < 4; r++){
        const int node = nb + quad*4 + r;
        if (node < N_NODES)
          out_root_b[(size_t)node*HID + (nt-4)*16 + col] = f2bf(d[r] + bv);
      }
    }
  }
}

// ====== GAT transform via MFMA -> HEAD-MAJOR xl, a_s, a_d ====================
__global__ __launch_bounds__(256) void k3_mfma(
    const ushort_t* __restrict__ h1b, const ushort_t* __restrict__ wgb,
    const float* __restrict__ att_src, const float* __restrict__ att_dst,
    ushort_t* __restrict__ xlb_hm, float* __restrict__ a_s_hm,
    float* __restrict__ a_d_hm)
{
  const int wid  = __builtin_amdgcn_readfirstlane(threadIdx.x >> 6);
  const int lane = threadIdx.x & 63;
  const int quad = lane >> 4, col = lane & 15;
  const int nb = blockIdx.x*64 + wid*16;
  const ushort_t* arow = h1b + (size_t)(nb + col)*HID + quad*8;
  short8 a0 = *(const short8*)(arow);
  short8 a1 = *(const short8*)(arow + 32);
  float as_acc[4] = {0,0,0,0}, ad_acc[4] = {0,0,0,0};
  #pragma unroll
  for (int nt = 0; nt < 16; nt++){
    short8 b0 = *(const short8*)(wgb + ((size_t)(nt*2+0)*64 + lane)*8);
    short8 b1 = *(const short8*)(wgb + ((size_t)(nt*2+1)*64 + lane)*8);
    f32x4 d = {0.f, 0.f, 0.f, 0.f};
    d = __builtin_amdgcn_mfma_f32_16x16x32_bf16(a0, b0, d, 0, 0, 0);
    d = __builtin_amdgcn_mfma_f32_16x16x32_bf16(a1, b1, d, 0, 0, 0);
    const int h = nt >> 2;
    const float asv = att_src[h*HID + (nt & 3)*16 + col];
    const float adv = att_dst[h*HID + (nt & 3)*16 + col];
    #pragma unroll
    for (int r = 0; r < 4; r++){
      const int node = nb + quad*4 + r;
      if (node < N_NODES)
        xlb_hm[(size_t)h*HS + (size_t)node*HID + (nt&3)*16 + col] = f2bf(d[r]);
      as_acc[r] += d[r]*asv;
      ad_acc[r] += d[r]*adv;
    }
    if ((nt & 3) == 3){                        // finish head h
      #pragma unroll
      for (int r = 0; r < 4; r++){
        float s1 = as_acc[r], s2 = ad_acc[r];
        #pragma unroll
        for (int off = 1; off < 16; off <<= 1){
          s1 += __shfl_xor(s1, off, 64);
          s2 += __shfl_xor(s2, off, 64);
        }
        const int node = nb + quad*4 + r;
        if (col == 0 && node < N_NODES){
          a_s_hm[h*NPH + node] = s1;
          a_d_hm[h*NPH + node] = s2;
        }
        as_acc[r] = 0.f; ad_acc[r] = 0.f;
      }
    }
  }
}

// -------- gather agg, A/B pair: block=node, 4 waves split the edge list ------
// Both variants: static-address slot int4 load issues at entry; 32 gathers
// unconditional (zeroed slot prefix -> junk hits node 0's hot row); validity
// applied at the accumulate.
// MODE 0 (VARIANT): 4-edge-per-instruction. Lanes split into 4 groups x 16;
//   group g covers edge w*8+g (j=0) and w*8+4+g (j=1); each lane loads uint2
//   (8B, 4 cols) -> 512B per gather instruction, 2 instructions per wave.
//   Index selected from wave-uniform pw[] via 2 cndmasks (NOT shfl).
//   Tests whether the ~53us floor is VMEM-transaction-bound.
// MODE 1 (CONTROL, byte-identical to round-4 v5): lane=column ushort gathers,
//   8 x 128B per wave; epilogue = fused global_add_pool atomics.
template<int MODE>
__global__ __launch_bounds__(256, 8) void k_aggb(
    const int* __restrict__ cnt, const ushort_t* __restrict__ slot,
    const ushort_t* __restrict__ featb, const ushort_t* __restrict__ rootb,
    const int* __restrict__ batch, float* __restrict__ g,
    ushort_t* __restrict__ outb)
{
  __shared__ float4 red4[48];                  // 768B; MODE1 uses as float[192]
  const int node = blockIdx.x;                 // grid exact: N_NODES
  const int w    = threadIdx.x >> 6;
  const int lane = threadIdx.x & 63;
  const ushort_t* __restrict__ sl = slot + (size_t)node*BUCKET;
  const int4 pk = ((const int4*)sl)[w];        // 8 u16 indices for this wave
  const int deg = min(cnt[node], BUCKET);
  const uint_t pw[4] = {(uint_t)pk.x, (uint_t)pk.y, (uint_t)pk.z, (uint_t)pk.w};

  if (MODE == 0){
    const int gi = lane >> 4, cl = lane & 15;
    // edge w*8+gi  -> u16 #gi  ; edge w*8+4+gi -> u16 #(4+gi)
    const uint_t hw0 = (gi & 2) ? pw[1] : pw[0];
    const uint_t s0  = (gi & 1) ? (hw0 >> 16) : (hw0 & 0xffffu);
    const uint_t hw1 = (gi & 2) ? pw[3] : pw[2];
    const uint_t s1  = (gi & 1) ? (hw1 >> 16) : (hw1 & 0xffffu);
    const uint2 r0 = ((const uint2*)(featb + (size_t)s0*HID))[cl];
    const uint2 r1 = ((const uint2*)(featb + (size_t)s1*HID))[cl];
    uint2 rt = {0u, 0u};
    if (w == 0) rt = ((const uint2*)(rootb + (size_t)node*HID))[cl];
    float a0=0.f, a1=0.f, a2=0.f, a3=0.f;
    if (w*8 + gi < deg){
      a0 += BF_LO(r0.x); a1 += BF_HI(r0.x);
      a2 += BF_LO(r0.y); a3 += BF_HI(r0.y);
    }
    if (w*8 + 4 + gi < deg){
      a0 += BF_LO(r1.x); a1 += BF_HI(r1.x);
      a2 += BF_LO(r1.y); a3 += BF_HI(r1.y);
    }
    if (w == 3 && gi == 0)
      for (int t = 32; t < deg; t++){          // astronomically rare tail
        const uint2 rr = ((const uint2*)(featb + (size_t)sl[t]*HID))[cl];
        a0 += BF_LO(rr.x); a1 += BF_HI(rr.x);
        a2 += BF_LO(rr.y); a3 += BF_HI(rr.y);
      }
    // cross-group reduce (per cl, over the 4 groups)
    a0 += __shfl_xor(a0,16,64); a1 += __shfl_xor(a1,16,64);
    a2 += __shfl_xor(a2,16,64); a3 += __shfl_xor(a3,16,64);
    a0 += __shfl_xor(a0,32,64); a1 += __shfl_xor(a1,32,64);
    a2 += __shfl_xor(a2,32,64); a3 += __shfl_xor(a3,32,64);
    if (w && gi == 0){
      float4 v; v.x=a0; v.y=a1; v.z=a2; v.w=a3;
      red4[(w-1)*16 + cl] = v;
    }
    __syncthreads();
    if (w == 0 && gi == 0){
      #pragma unroll
      for (int b = 0; b < 3; b++){
        const float4 rr = red4[b*16 + cl];
        a0 += rr.x; a1 += rr.y; a2 += rr.z; a3 += rr.w;
      }
      a0 += BF_LO(rt.x); a1 += BF_HI(rt.x);
      a2 += BF_LO(rt.y); a3 += BF_HI(rt.y);
      const float v0 = fmaxf(a0, 0.f), v1 = fmaxf(a1, 0.f);
      const float v2 = fmaxf(a2, 0.f), v3 = fmaxf(a3, 0.f);
      uint2 o;
      o.x = (uint_t)f2bf(v0) | ((uint_t)f2bf(v1) << 16);
      o.y = (uint_t)f2bf(v2) | ((uint_t)f2bf(v3) << 16);
      ((uint2*)(outb + (size_t)node*HID))[cl] = o;
    }
  } else {
    float* red = (float*)red4;
    uint_t rt = 0;
    if (w == 0) rt = rootb[(size_t)node*HID + lane];
    uint_t u[8];
    #pragma unroll
    for (int j = 0; j < 8; j++){
      const uint_t s = (j & 1) ? (pw[j>>1] >> 16) : (pw[j>>1] & 0xffffu);
      u[j] = featb[(size_t)s*HID + lane];      // unconditional
    }
    float acc = 0.f;
    #pragma unroll
    for (int j = 0; j < 8; j++)
      acc += (w*8 + j < deg) ? BF_LO(u[j]) : 0.f;
    if (w == 3)
      for (int t = 32; t < deg; t++)           // astronomically rare tail
        acc += BF_LO((uint_t)featb[(size_t)sl[t]*HID + lane]);
    if (w) red[(w-1)*HID + lane] = acc;
    __syncthreads();
    if (w == 0){
      acc += red[lane] + red[HID + lane] + red[2*HID + lane];
      acc += BF_LO(rt);
      const float v = fmaxf(acc, 0.f);
      const int b = batch[node];               // wave-uniform
      atomicAdd(&g[b*HID + lane], v);
    }
  }
}

// ---- GAT softmax+aggregate v6: head-per-block, 16-lane group = 1 node -------
__global__ __launch_bounds__(256) void k_gat_node(
    const int* __restrict__ cnt, const ushort_t* __restrict__ slot,
    const ushort_t* __restrict__ xlb_hm, const float* __restrict__ a_s_hm,
    const float* __restrict__ a_d_hm, const float* __restrict__ bg,
    ushort_t* __restrict__ h2b_hm)
{
  const int head = blockIdx.x & 3;
  const int node = (blockIdx.x >> 2)*16 + (threadIdx.x >> 4);
  if (node >= N_NODES) return;                 // whole 16-lane group exits
  const int lane = threadIdx.x & 63;
  const int cl = lane & 15;
  const int gb = lane & 48;                    // group base within wave
  const ushort_t* __restrict__ sl = slot + (size_t)node*BUCKET;
  const int deg = min(cnt[node], BUCKET);
  const ushort_t* __restrict__ xlh = xlb_hm + (size_t)head*HS;
  const float* __restrict__ ash = a_s_hm + head*NPH;
  const float adh = a_d_hm[head*NPH + node];
  float acc0=0, acc1=0, acc2=0, acc3=0;
  float dsum = 0.f;
  for (int base = 0; base < deg; base += 16){
    // phase 1: lane cl owns edge base+cl -> exp once per (edge,head)
    float pme = 0.f; int sme = node;
    const int e = base + cl;
    if (e < deg){
      sme = sl[e];
      pme = __expf(lrelu(ash[sme] + adh));
    }
    dsum += pme;
    // phase 2: stream the chunk's edges through the 16-lane group, unroll x2
    const int nsub = min(16, deg - base);
    int s = 0;
    for (; s + 2 <= nsub; s += 2){
      const float pA = __shfl(pme, gb + s, 64);
      const int   sA = __shfl(sme, gb + s, 64);
      const float pB = __shfl(pme, gb + s + 1, 64);
      const int   sB = __shfl(sme, gb + s + 1, 64);
      uint2 rA = ((const uint2*)(xlh + (size_t)sA*HID))[cl];
      uint2 rB = ((const uint2*)(xlh + (size_t)sB*HID))[cl];
      acc0 += pA*BF_LO(rA.x); acc1 += pA*BF_HI(rA.x);
      acc2 += pA*BF_LO(rA.y); acc3 += pA*BF_HI(rA.y);
      acc0 += pB*BF_LO(rB.x); acc1 += pB*BF_HI(rB.x);
      acc2 += pB*BF_LO(rB.y); acc3 += pB*BF_HI(rB.y);
    }
    if (s < nsub){
      const float pA = __shfl(pme, gb + s, 64);
      const int   sA = __shfl(sme, gb + s, 64);
      uint2 rA = ((const uint2*)(xlh + (size_t)sA*HID))[cl];
      acc0 += pA*BF_LO(rA.x); acc1 += pA*BF_HI(rA.x);
      acc2 += pA*BF_LO(rA.y); acc3 += pA*BF_HI(rA.y);
    }
  }
  // denom reduce within the 16-lane group
  #pragma unroll
  for (int off = 1; off < 16; off <<= 1) dsum += __shfl_xor(dsum, off, 64);
  // self loop + epilogue (all 16 lanes write their cols)
  const float pself = __expf(lrelu(ash[node] + adh));
  const float inv = 1.f / (dsum + pself);
  uint2 r = ((const uint2*)(xlh + (size_t)node*HID))[cl];
  acc0 += pself*BF_LO(r.x); acc1 += pself*BF_HI(r.x);
  acc2 += pself*BF_LO(r.y); acc3 += pself*BF_HI(r.y);
  const int col0 = head*HID + cl*4;
  const float ox = fmaxf(acc0*inv + bg[col0+0], 0.f);
  const float oy = fmaxf(acc1*inv + bg[col0+1], 0.f);
  const float oz = fmaxf(acc2*inv + bg[col0+2], 0.f);
  const float ow = fmaxf(acc3*inv + bg[col0+3], 0.f);
  uint2 o;
  o.x = (uint_t)f2bf(ox) | ((uint_t)f2bf(oy) << 16);
  o.y = (uint_t)f2bf(oz) | ((uint_t)f2bf(ow) << 16);
  ((uint2*)(h2b_hm + (size_t)head*HS + (size_t)node*HID))[cl] = o;
}

__global__ __launch_bounds__(256) void k_head(
    const float* __restrict__ g, const float* __restrict__ W1,
    const float* __restrict__ b1, const float* __restrict__ W2,
    const float* __restrict__ b2, float* __restrict__ out)
{
  __shared__ float gs[NUM_GRAPHS*HID];
  __shared__ float hh[NUM_GRAPHS*HID];
  for (int i = threadIdx.x; i < NUM_GRAPHS*HID; i += 256) gs[i] = g[i];
  __syncthreads();
  for (int t = threadIdx.x; t < NUM_GRAPHS*HID; t += 256){
    int b = t >> 6, j = t & 63;
    float acc = b1[j];
    for (int k = 0; k < HID; k++) acc += gs[b*HID+k]*W1[k*HID+j];
    hh[t] = fmaxf(acc, 0.f);
  }
  __syncthreads();
  for (int t = threadIdx.x; t < NUM_GRAPHS*2; t += 256){
    int b = t >> 1, c = t & 1;
    float acc = b2[c];
    for (int k = 0; k < HID; k++) acc += hh[b*HID+k]*W2[k*2+c];
    out[t] = 1.f / (1.f + __expf(-acc));
  }
}

extern "C" void kernel_launch(void* const* d_in, const int* in_sizes, int n_in,
                              void* d_out, int out_size, void* d_ws, size_t ws_size,
                              hipStream_t stream)
{
  const float* x       = (const float*)d_in[0];
  const int*   ei      = (const int*)d_in[1];
  const int*   batch   = (const int*)d_in[2];
  const float* W1_rel  = (const float*)d_in[3];
  const float* b1      = (const float*)d_in[4];
  const float* W1_root = (const float*)d_in[5];
  const float* Wg      = (const float*)d_in[6];
  const float* att_src = (const float*)d_in[7];
  const float* att_dst = (const float*)d_in[8];
  const float* bg      = (const float*)d_in[9];
  const float* W5_rel  = (const float*)d_in[10];
  const float* b5      = (const float*)d_in[11];
  const float* W5_root = (const float*)d_in[12];
  const float* W_fc1   = (const float*)d_in[13];
  const float* b_fc1   = (const float*)d_in[14];
  const float* W_fc2   = (const float*)d_in[15];
  const float* b_fc2   = (const float*)d_in[16];
  const int* src = ei;
  const int* dst = ei + N_EDGES;

  // ---- workspace layout, FLOAT (4-byte) units (bf16 count = 2x fu) ---------
  float* ws    = (float*)d_ws;
  ushort_t* xr_b   = (ushort_t*)ws;             // rel bf16  [0, 800800)
  ushort_t* rootb  = (ushort_t*)(ws + 800800);  // root bf16
  ushort_t* h1b    = (ushort_t*)(ws + 2402400); // [2402400,  3203200)
  ushort_t* xlb_hm = (ushort_t*)(ws + 3203200); // [3203200,  6406304)
  float*    a_s_hm = ws + 6406304;              // [6406304,  6508704)
  float*    a_d_hm = ws + 6508704;              // [6508704,  6611104)
  ushort_t* h2b_hm = (ushort_t*)(ws + 6611104); // [6611104,  9814200)
  float*    g      = ws + 9814200;              // [9814200,  9818296)
  int*      cnt    = (int*)(ws + 9818296);      // [9818296,  9843296)  (g|cnt contiguous)
  ushort_t* wc1b   = (ushort_t*)(ws + 9843296); // [9843296,  9851488)
  ushort_t* wc5b   = (ushort_t*)(ws + 9851488); // [9851488,  9867872)
  ushort_t* wgb    = (ushort_t*)(ws + 9867872); // [9867872,  9876064)
  ushort_t* slot   = (ushort_t*)(ws + 9876064); // ushort slots
  float*    out    = (float*)d_out;

  // init: zero g+cnt+slot-prefix + pack all weights
  k_init<<<64,256,0,stream>>>(W1_rel, W1_root, W5_rel, W5_root, Wg,
                              wc1b, wc5b, wgb, g, slot);

  // fused CSR scatter + conv1 MFMA (independent halves, one dispatch)
  k_c1_fill<<<FILL_BLOCKS + (N_NODES+63)/64,256,0,stream>>>(
      src, dst, cnt, slot, x, wc1b, b1, xr_b, rootb);

  // agg -> h1 bf16 (VARIANT: 4-edge uint2 gathers)
  k_aggb<0><<<N_NODES,256,0,stream>>>(cnt, slot, xr_b, rootb,
                                      nullptr, nullptr, h1b);

  // GAT: MFMA transform + softmax-agg
  k3_mfma<<<(N_NODES+63)/64,256,0,stream>>>(h1b, wgb, att_src, att_dst,
                                            xlb_hm, a_s_hm, a_d_hm);
  k_gat_node<<<((N_NODES+15)/16)*HEADS,256,0,stream>>>(cnt, slot,
      xlb_hm, a_s_hm, a_d_hm, bg, h2b_hm);

  // conv5 (MFMA, head-major A) + agg fused with global_add_pool
  // (CONTROL: round-4 8x128B gather structure, unchanged)
  conv5_mfma<<<(N_NODES+63)/64,256,0,stream>>>(h2b_hm, wc5b, b5, xr_b, rootb);
  k_aggb<1><<<N_NODES,256,0,stream>>>(cnt, slot, xr_b, rootb,
                                      batch, g, nullptr);

  // head
  k_head<<<1,256,0,stream>>>(g, W_fc1, b_fc1, W_fc2, b_fc2, out);
}

// Round 8
// 258.956 us; speedup vs baseline: 1.2011x; 1.0119x over previous
//
#include <hip/hip_runtime.h>
#include <math.h>

#define N_NODES 25000
#define N_EDGES 400000
#define FEAT 128
#define HID 64
#define HEADS 4
#define HH 256   // HEADS*HID
#define NUM_GRAPHS 64
#define BUCKET 96     // max in-degree slots (mean 16, sigma 4 -> P(>96)~1e-80)
#define HS 1601536    // head-major slice stride in ushorts = 25024*64
#define NPH 25600     // head-major stride for a_s/a_d (floats)
#define FILL_BLOCKS 1563   // ceil(N_EDGES/256)

typedef unsigned short ushort_t;
typedef unsigned int uint_t;
typedef __attribute__((ext_vector_type(8))) short short8;   // 8 bf16 (4 VGPRs)
typedef __attribute__((ext_vector_type(4))) float f32x4;

__device__ __forceinline__ float lrelu(float x){ return x > 0.f ? x : 0.2f*x; }

// fp32 -> bf16 with round-to-nearest-even
__device__ __forceinline__ ushort_t f2bf(float f){
  uint_t u = __float_as_uint(f);
  return (ushort_t)((u + 0x7fffu + ((u >> 16) & 1u)) >> 16);
}
#define BF_LO(u) __uint_as_float((u) << 16)
#define BF_HI(u) __uint_as_float((u) & 0xffff0000u)

// ====== init: zero g+cnt+slot-prefix, pack all MFMA weight fragments ========
__global__ __launch_bounds__(256) void k_init(
    const float* __restrict__ W1_rel, const float* __restrict__ W1_root,
    const float* __restrict__ W5_rel, const float* __restrict__ W5_root,
    const float* __restrict__ Wg,
    ushort_t* __restrict__ wc1b, ushort_t* __restrict__ wc5b,
    ushort_t* __restrict__ wgb, float* __restrict__ g /* g|cnt contiguous */,
    ushort_t* __restrict__ slot)
{
  const int e = blockIdx.x*256 + threadIdx.x;   // 64 blocks -> e in [0,16384)
  { // conv1 [Wrel|Wroot] 128x128: nt<8, kc<4
    int j=e&7, lane=(e>>3)&63, kc=(e>>9)&3, nt=e>>11;
    int k = kc*32 + (lane>>4)*8 + j, n = nt*16 + (lane&15);
    float v = (n < 64) ? W1_rel[k*64 + n] : W1_root[k*64 + n - 64];
    wc1b[e] = f2bf(v);
  }
  { // Wg 64x256: nt<16, kt<2
    int j=e&7, lane=(e>>3)&63, kt=(e>>9)&1, nt=e>>10;
    int k = kt*32 + (lane>>4)*8 + j, n = nt*16 + (lane&15);
    wgb[e] = f2bf(Wg[k*HH + n]);
  }
  #pragma unroll
  for (int e5 = e; e5 < 32768; e5 += 16384){ // conv5 256x128: nt<8, kc<8
    int j=e5&7, lane=(e5>>3)&63, kc=(e5>>9)&7, nt=e5>>12;
    int k = kc*32 + (lane>>4)*8 + j, n = nt*16 + (lane&15);
    float v = (n < 64) ? W5_rel[k*64 + n] : W5_root[k*64 + n - 64];
    wc5b[e5] = f2bf(v);
  }
  // zero g (4096 f32) + cnt (25000 int), laid out contiguously after g
  int* z = (int*)g;
  for (int i = e; i < 4096 + N_NODES; i += 16384) z[i] = 0;
  // zero first 32 slots of every row: aggregators gather those 32 indices
  // UNCONDITIONALLY; zeroed junk -> node 0's cache-hot row (safe + cheap).
  const uint4 zz = {0,0,0,0};
  for (int n = e; n < N_NODES; n += 16384){
    uint4* p = (uint4*)(slot + (size_t)n*BUCKET);   // row = 192B, 16B-aligned
    p[0] = zz; p[1] = zz; p[2] = zz; p[3] = zz;     // first 64B = 32 ushorts
  }
}

// ====== fused: CSR bucket scatter (blocks [0,FILL_BLOCKS)) + conv1 MFMA ======
__global__ __launch_bounds__(256) void k_c1_fill(
    const int* __restrict__ src, const int* __restrict__ dst,
    int* __restrict__ cnt, ushort_t* __restrict__ slot,
    const float* __restrict__ X, const ushort_t* __restrict__ wc1b,
    const float* __restrict__ bias,
    ushort_t* __restrict__ out_rel_b, ushort_t* __restrict__ out_root_b)
{
  if (blockIdx.x < FILL_BLOCKS){
    const int e = blockIdx.x*256 + threadIdx.x;
    if (e < N_EDGES){
      int d = dst[e];
      int pos = atomicAdd(&cnt[d], 1);
      if (pos < BUCKET) slot[(size_t)d*BUCKET + pos] = (ushort_t)src[e];
    }
    return;
  }
  // conv1: [rel|root] = x @ [Wrel|Wroot], K=128, M=128
  const int wid  = __builtin_amdgcn_readfirstlane(threadIdx.x >> 6);
  const int lane = threadIdx.x & 63;
  const int quad = lane >> 4, col = lane & 15;
  const int nb = (blockIdx.x - FILL_BLOCKS)*64 + wid*16;
  if (nb >= N_NODES) return;
  const int row = min(nb + col, N_NODES-1);
  const float* __restrict__ xr = X + (size_t)row*FEAT + quad*8;
  short8 a[4];
  #pragma unroll
  for (int kc = 0; kc < 4; kc++){
    #pragma unroll
    for (int j = 0; j < 8; j++)
      ((ushort_t*)&a[kc])[j] = f2bf(xr[kc*32 + j]);
  }
  #pragma unroll
  for (int nt = 0; nt < 8; nt++){
    f32x4 d = {0.f,0.f,0.f,0.f};
    #pragma unroll
    for (int kc = 0; kc < 4; kc++){
      short8 b = *(const short8*)(wc1b + ((size_t)(nt*4+kc)*64 + lane)*8);
      d = __builtin_amdgcn_mfma_f32_16x16x32_bf16(a[kc], b, d, 0, 0, 0);
    }
    if (nt < 4){
      #pragma unroll
      for (int r = 0; r < 4; r++){
        const int node = nb + quad*4 + r;
        if (node < N_NODES)
          out_rel_b[(size_t)node*HID + nt*16 + col] = f2bf(d[r]);
      }
    } else {
      const float bv = bias[(nt-4)*16 + col];
      #pragma unroll
      for (int r = 0; r < 4; r++){
        const int node = nb + quad*4 + r;
        if (node < N_NODES)
          out_root_b[(size_t)node*HID + (nt-4)*16 + col] = f2bf(d[r] + bv);
      }
    }
  }
}

// ====== conv5 via MFMA: A from HEAD-MAJOR h2b ================================
__global__ __launch_bounds__(256) void conv5_mfma(
    const ushort_t* __restrict__ h2b_hm, const ushort_t* __restrict__ wc5b,
    const float* __restrict__ bias,
    ushort_t* __restrict__ out_rel_b, ushort_t* __restrict__ out_root_b)
{
  const int wid  = __builtin_amdgcn_readfirstlane(threadIdx.x >> 6);
  const int lane = threadIdx.x & 63;
  const int quad = lane >> 4, col = lane & 15;
  const int nb = blockIdx.x*64 + wid*16;
  if (nb >= N_NODES) return;
  const int row = nb + col;                    // < 25024 (padded slices)
  short8 a[8];
  #pragma unroll
  for (int kc = 0; kc < 8; kc++){
    const int k0 = kc*32 + quad*8;             // 8-chunk never crosses a head
    a[kc] = *(const short8*)(h2b_hm + (size_t)(k0>>6)*HS
                             + (size_t)row*HID + (k0&63));
  }
  #pragma unroll
  for (int nt = 0; nt < 8; nt++){
    f32x4 d = {0.f,0.f,0.f,0.f};
    #pragma unroll
    for (int kc = 0; kc < 8; kc++){
      short8 b = *(const short8*)(wc5b + ((size_t)(nt*8+kc)*64 + lane)*8);
      d = __builtin_amdgcn_mfma_f32_16x16x32_bf16(a[kc], b, d, 0, 0, 0);
    }
    if (nt < 4){
      #pragma unroll
      for (int r = 0; r < 4; r++){
        const int node = nb + quad*4 + r;
        if (node < N_NODES)
          out_rel_b[(size_t)node*HID + nt*16 + col] = f2bf(d[r]);
      }
    } else {
      const float bv = bias[(nt-4)*16 + col];
      #pragma unroll
      for (int r = 0; r < 4; r++){
        const int node = nb + quad*4 + r;
        if (node < N_NODES)
          out_root_b[(size_t)node*HID + (nt-4)*16 + col] = f2bf(d[r] + bv);
      }
    }
  }
}

// ---------- helpers for the fused agg phase (all static indexing) -----------
__device__ __forceinline__ void agg_ldslot(
    const int* __restrict__ cnt, const ushort_t* __restrict__ slot,
    const ushort_t* __restrict__ rootb, int nv, int lane,
    uint_t pw[16], int &deg, uint_t &rt)
{
  const ushort_t* __restrict__ sl = slot + (size_t)nv*BUCKET;
  const int4 A = ((const int4*)sl)[0];
  const int4 B = ((const int4*)sl)[1];
  const int4 C = ((const int4*)sl)[2];
  const int4 D = ((const int4*)sl)[3];
  pw[0]=(uint_t)A.x; pw[1]=(uint_t)A.y; pw[2]=(uint_t)A.z; pw[3]=(uint_t)A.w;
  pw[4]=(uint_t)B.x; pw[5]=(uint_t)B.y; pw[6]=(uint_t)B.z; pw[7]=(uint_t)B.w;
  pw[8]=(uint_t)C.x; pw[9]=(uint_t)C.y; pw[10]=(uint_t)C.z; pw[11]=(uint_t)C.w;
  pw[12]=(uint_t)D.x; pw[13]=(uint_t)D.y; pw[14]=(uint_t)D.z; pw[15]=(uint_t)D.w;
  deg = min(cnt[nv], BUCKET);
  rt  = rootb[(size_t)nv*HID + lane];
}
__device__ __forceinline__ void agg_gather(
    const ushort_t* __restrict__ featb, const uint_t pw[16], int lane,
    uint_t u[32])
{
  #pragma unroll
  for (int j = 0; j < 32; j++){
    const uint_t s = (j & 1) ? (pw[j>>1] >> 16) : (pw[j>>1] & 0xffffu);
    u[j] = featb[(size_t)s*HID + lane];        // unconditional (zeroed junk)
  }
}
__device__ __forceinline__ float agg_acc(const uint_t u[32], int deg, uint_t rt)
{
  float acc = BF_LO(rt);
  #pragma unroll
  for (int j = 0; j < 32; j++)
    acc += (j < deg) ? BF_LO(u[j]) : 0.f;
  return acc;
}

// ====== FUSED: conv1-agg (phase A, gathers hidden under phase B MFMA of
// co-resident blocks) + GAT transform (phase B = old k3_mfma body) ===========
// Block = 64 nodes, 4 waves. Wave wid aggregates its 16 MFMA A-rows into an
// LDS tile (depth-2 pipeline: pair k+1's slot+gathers issue before pair k's
// accumulate), then phase B consumes the tile as A-fragments.
// Removes the standalone latency-bound agg dispatch AND the h1b round-trip.
__global__ __launch_bounds__(256) void k_agg3(
    const int* __restrict__ cnt, const ushort_t* __restrict__ slot,
    const ushort_t* __restrict__ featb, const ushort_t* __restrict__ rootb,
    const ushort_t* __restrict__ wgb,
    const float* __restrict__ att_src, const float* __restrict__ att_dst,
    ushort_t* __restrict__ xlb_hm, float* __restrict__ a_s_hm,
    float* __restrict__ a_d_hm)
{
  __shared__ ushort_t h1s[64][80];             // 160B row stride (16B-aligned)
  const int wid  = __builtin_amdgcn_readfirstlane(threadIdx.x >> 6);
  const int lane = threadIdx.x & 63;
  const int nb = blockIdx.x*64;                // grid exact: 391 blocks
  const int rbase = wid*16;
  const int nb0 = nb + rbase;

  // ---- phase A: aggregate 16 nodes (2-node pipeline stages) ----
  {
    uint_t pwA[16], pwB[16], uA[32], uB[32], rtA, rtB;
    int degA, degB;
    agg_ldslot(cnt, slot, rootb, min(nb0+0, N_NODES-1), lane, pwA, degA, rtA);
    agg_ldslot(cnt, slot, rootb, min(nb0+1, N_NODES-1), lane, pwB, degB, rtB);
    agg_gather(featb, pwA, lane, uA);
    agg_gather(featb, pwB, lane, uB);
    for (int k = 0; k < 8; k++){
      float aA = agg_acc(uA, degA, rtA);
      float aB = agg_acc(uB, degB, rtB);
      if (degA > 32){                          // astronomically rare tail
        const ushort_t* sl = slot + (size_t)min(nb0+2*k,   N_NODES-1)*BUCKET;
        for (int t = 32; t < degA; t++)
          aA += BF_LO((uint_t)featb[(size_t)sl[t]*HID + lane]);
      }
      if (degB > 32){
        const ushort_t* sl = slot + (size_t)min(nb0+2*k+1, N_NODES-1)*BUCKET;
        for (int t = 32; t < degB; t++)
          aB += BF_LO((uint_t)featb[(size_t)sl[t]*HID + lane]);
      }
      h1s[rbase + 2*k    ][lane] = f2bf(fmaxf(aA, 0.f));
      h1s[rbase + 2*k + 1][lane] = f2bf(fmaxf(aB, 0.f));
      if (k < 7){
        agg_ldslot(cnt, slot, rootb, min(nb0+2*k+2, N_NODES-1), lane,
                   pwA, degA, rtA);
        agg_ldslot(cnt, slot, rootb, min(nb0+2*k+3, N_NODES-1), lane,
                   pwB, degB, rtB);
        agg_gather(featb, pwA, lane, uA);
        agg_gather(featb, pwB, lane, uB);
      }
    }
  }
  __syncthreads();

  // ---- phase B: GAT transform (old k3_mfma body, A from LDS) ----
  const int quad = lane >> 4, col = lane & 15;
  short8 a0 = *(const short8*)&h1s[rbase + col][quad*8];
  short8 a1 = *(const short8*)&h1s[rbase + col][quad*8 + 32];
  float as_acc[4] = {0,0,0,0}, ad_acc[4] = {0,0,0,0};
  #pragma unroll
  for (int nt = 0; nt < 16; nt++){
    short8 b0 = *(const short8*)(wgb + ((size_t)(nt*2+0)*64 + lane)*8);
    short8 b1 = *(const short8*)(wgb + ((size_t)(nt*2+1)*64 + lane)*8);
    f32x4 d = {0.f, 0.f, 0.f, 0.f};
    d = __builtin_amdgcn_mfma_f32_16x16x32_bf16(a0, b0, d, 0, 0, 0);
    d = __builtin_amdgcn_mfma_f32_16x16x32_bf16(a1, b1, d, 0, 0, 0);
    const int h = nt >> 2;
    const float asv = att_src[h*HID + (nt & 3)*16 + col];
    const float adv = att_dst[h*HID + (nt & 3)*16 + col];
    #pragma unroll
    for (int r = 0; r < 4; r++){
      const int node = nb0 + quad*4 + r;
      if (node < N_NODES)
        xlb_hm[(size_t)h*HS + (size_t)node*HID + (nt&3)*16 + col] = f2bf(d[r]);
      as_acc[r] += d[r]*asv;
      ad_acc[r] += d[r]*adv;
    }
    if ((nt & 3) == 3){                        // finish head h
      #pragma unroll
      for (int r = 0; r < 4; r++){
        float s1 = as_acc[r], s2 = ad_acc[r];
        #pragma unroll
        for (int off = 1; off < 16; off <<= 1){
          s1 += __shfl_xor(s1, off, 64);
          s2 += __shfl_xor(s2, off, 64);
        }
        const int node = nb0 + quad*4 + r;
        if (col == 0 && node < N_NODES){
          a_s_hm[h*NPH + node] = s1;
          a_d_hm[h*NPH + node] = s2;
        }
        as_acc[r] = 0.f; ad_acc[r] = 0.f;
      }
    }
  }
}

// -------- pool-side gather agg (round-4 proven structure): block=node,
// 4 waves split the edge list; unconditional gathers; fused global_add_pool.
__global__ __launch_bounds__(256, 8) void k_aggb(
    const int* __restrict__ cnt, const ushort_t* __restrict__ slot,
    const ushort_t* __restrict__ featb, const ushort_t* __restrict__ rootb,
    const int* __restrict__ batch, float* __restrict__ g)
{
  __shared__ float red[3*HID];
  const int node = blockIdx.x;                 // grid exact: N_NODES
  const int w    = threadIdx.x >> 6;
  const int lane = threadIdx.x & 63;
  const ushort_t* __restrict__ sl = slot + (size_t)node*BUCKET;
  const int4 pk = ((const int4*)sl)[w];        // 8 u16 indices for this wave
  uint_t rt = 0;
  if (w == 0) rt = rootb[(size_t)node*HID + lane];
  const int deg = min(cnt[node], BUCKET);
  const uint_t pw[4] = {(uint_t)pk.x, (uint_t)pk.y, (uint_t)pk.z, (uint_t)pk.w};
  uint_t u[8];
  #pragma unroll
  for (int j = 0; j < 8; j++){
    const uint_t s = (j & 1) ? (pw[j>>1] >> 16) : (pw[j>>1] & 0xffffu);
    u[j] = featb[(size_t)s*HID + lane];        // unconditional
  }
  float acc = 0.f;
  #pragma unroll
  for (int j = 0; j < 8; j++)
    acc += (w*8 + j < deg) ? BF_LO(u[j]) : 0.f;
  if (w == 3)
    for (int t = 32; t < deg; t++)             // astronomically rare tail
      acc += BF_LO((uint_t)featb[(size_t)sl[t]*HID + lane]);
  if (w) red[(w-1)*HID + lane] = acc;
  __syncthreads();
  if (w == 0){
    acc += red[lane] + red[HID + lane] + red[2*HID + lane];
    acc += BF_LO(rt);
    const float v = fmaxf(acc, 0.f);
    const int b = batch[node];                 // wave-uniform
    atomicAdd(&g[b*HID + lane], v);
  }
}

// ---- GAT softmax+aggregate v6: head-per-block, 16-lane group = 1 node -------
__global__ __launch_bounds__(256) void k_gat_node(
    const int* __restrict__ cnt, const ushort_t* __restrict__ slot,
    const ushort_t* __restrict__ xlb_hm, const float* __restrict__ a_s_hm,
    const float* __restrict__ a_d_hm, const float* __restrict__ bg,
    ushort_t* __restrict__ h2b_hm)
{
  const int head = blockIdx.x & 3;
  const int node = (blockIdx.x >> 2)*16 + (threadIdx.x >> 4);
  if (node >= N_NODES) return;                 // whole 16-lane group exits
  const int lane = threadIdx.x & 63;
  const int cl = lane & 15;
  const int gb = lane & 48;                    // group base within wave
  const ushort_t* __restrict__ sl = slot + (size_t)node*BUCKET;
  const int deg = min(cnt[node], BUCKET);
  const ushort_t* __restrict__ xlh = xlb_hm + (size_t)head*HS;
  const float* __restrict__ ash = a_s_hm + head*NPH;
  const float adh = a_d_hm[head*NPH + node];
  float acc0=0, acc1=0, acc2=0, acc3=0;
  float dsum = 0.f;
  for (int base = 0; base < deg; base += 16){
    // phase 1: lane cl owns edge base+cl -> exp once per (edge,head)
    float pme = 0.f; int sme = node;
    const int e = base + cl;
    if (e < deg){
      sme = sl[e];
      pme = __expf(lrelu(ash[sme] + adh));
    }
    dsum += pme;
    // phase 2: stream the chunk's edges through the 16-lane group, unroll x2
    const int nsub = min(16, deg - base);
    int s = 0;
    for (; s + 2 <= nsub; s += 2){
      const float pA = __shfl(pme, gb + s, 64);
      const int   sA = __shfl(sme, gb + s, 64);
      const float pB = __shfl(pme, gb + s + 1, 64);
      const int   sB = __shfl(sme, gb + s + 1, 64);
      uint2 rA = ((const uint2*)(xlh + (size_t)sA*HID))[cl];
      uint2 rB = ((const uint2*)(xlh + (size_t)sB*HID))[cl];
      acc0 += pA*BF_LO(rA.x); acc1 += pA*BF_HI(rA.x);
      acc2 += pA*BF_LO(rA.y); acc3 += pA*BF_HI(rA.y);
      acc0 += pB*BF_LO(rB.x); acc1 += pB*BF_HI(rB.x);
      acc2 += pB*BF_LO(rB.y); acc3 += pB*BF_HI(rB.y);
    }
    if (s < nsub){
      const float pA = __shfl(pme, gb + s, 64);
      const int   sA = __shfl(sme, gb + s, 64);
      uint2 rA = ((const uint2*)(xlh + (size_t)sA*HID))[cl];
      acc0 += pA*BF_LO(rA.x); acc1 += pA*BF_HI(rA.x);
      acc2 += pA*BF_LO(rA.y); acc3 += pA*BF_HI(rA.y);
    }
  }
  // denom reduce within the 16-lane group
  #pragma unroll
  for (int off = 1; off < 16; off <<= 1) dsum += __shfl_xor(dsum, off, 64);
  // self loop + epilogue (all 16 lanes write their cols)
  const float pself = __expf(lrelu(ash[node] + adh));
  const float inv = 1.f / (dsum + pself);
  uint2 r = ((const uint2*)(xlh + (size_t)node*HID))[cl];
  acc0 += pself*BF_LO(r.x); acc1 += pself*BF_HI(r.x);
  acc2 += pself*BF_LO(r.y); acc3 += pself*BF_HI(r.y);
  const int col0 = head*HID + cl*4;
  const float ox = fmaxf(acc0*inv + bg[col0+0], 0.f);
  const float oy = fmaxf(acc1*inv + bg[col0+1], 0.f);
  const float oz = fmaxf(acc2*inv + bg[col0+2], 0.f);
  const float ow = fmaxf(acc3*inv + bg[col0+3], 0.f);
  uint2 o;
  o.x = (uint_t)f2bf(ox) | ((uint_t)f2bf(oy) << 16);
  o.y = (uint_t)f2bf(oz) | ((uint_t)f2bf(ow) << 16);
  ((uint2*)(h2b_hm + (size_t)head*HS + (size_t)node*HID))[cl] = o;
}

__global__ __launch_bounds__(256) void k_head(
    const float* __restrict__ g, const float* __restrict__ W1,
    const float* __restrict__ b1, const float* __restrict__ W2,
    const float* __restrict__ b2, float* __restrict__ out)
{
  __shared__ float gs[NUM_GRAPHS*HID];
  __shared__ float hh[NUM_GRAPHS*HID];
  for (int i = threadIdx.x; i < NUM_GRAPHS*HID; i += 256) gs[i] = g[i];
  __syncthreads();
  for (int t = threadIdx.x; t < NUM_GRAPHS*HID; t += 256){
    int b = t >> 6, j = t & 63;
    float acc = b1[j];
    for (int k = 0; k < HID; k++) acc += gs[b*HID+k]*W1[k*HID+j];
    hh[t] = fmaxf(acc, 0.f);
  }
  __syncthreads();
  for (int t = threadIdx.x; t < NUM_GRAPHS*2; t += 256){
    int b = t >> 1, c = t & 1;
    float acc = b2[c];
    for (int k = 0; k < HID; k++) acc += hh[b*HID+k]*W2[k*2+c];
    out[t] = 1.f / (1.f + __expf(-acc));
  }
}

extern "C" void kernel_launch(void* const* d_in, const int* in_sizes, int n_in,
                              void* d_out, int out_size, void* d_ws, size_t ws_size,
                              hipStream_t stream)
{
  const float* x       = (const float*)d_in[0];
  const int*   ei      = (const int*)d_in[1];
  const int*   batch   = (const int*)d_in[2];
  const float* W1_rel  = (const float*)d_in[3];
  const float* b1      = (const float*)d_in[4];
  const float* W1_root = (const float*)d_in[5];
  const float* Wg      = (const float*)d_in[6];
  const float* att_src = (const float*)d_in[7];
  const float* att_dst = (const float*)d_in[8];
  const float* bg      = (const float*)d_in[9];
  const float* W5_rel  = (const float*)d_in[10];
  const float* b5      = (const float*)d_in[11];
  const float* W5_root = (const float*)d_in[12];
  const float* W_fc1   = (const float*)d_in[13];
  const float* b_fc1   = (const float*)d_in[14];
  const float* W_fc2   = (const float*)d_in[15];
  const float* b_fc2   = (const float*)d_in[16];
  const int* src = ei;
  const int* dst = ei + N_EDGES;

  // ---- workspace layout, FLOAT (4-byte) units (bf16 count = 2x fu) ---------
  float* ws    = (float*)d_ws;
  ushort_t* xr_b   = (ushort_t*)ws;             // rel bf16  [0, 800800)
  ushort_t* rootb  = (ushort_t*)(ws + 800800);  // root bf16
  ushort_t* xlb_hm = (ushort_t*)(ws + 3203200); // [3203200,  6406304)
  float*    a_s_hm = ws + 6406304;              // [6406304,  6508704)
  float*    a_d_hm = ws + 6508704;              // [6508704,  6611104)
  ushort_t* h2b_hm = (ushort_t*)(ws + 6611104); // [6611104,  9814200)
  float*    g      = ws + 9814200;              // [9814200,  9818296)
  int*      cnt    = (int*)(ws + 9818296);      // [9818296,  9843296)  (g|cnt contiguous)
  ushort_t* wc1b   = (ushort_t*)(ws + 9843296); // [9843296,  9851488)
  ushort_t* wc5b   = (ushort_t*)(ws + 9851488); // [9851488,  9867872)
  ushort_t* wgb    = (ushort_t*)(ws + 9867872); // [9867872,  9876064)
  ushort_t* slot   = (ushort_t*)(ws + 9876064); // ushort slots
  float*    out    = (float*)d_out;

  // init: zero g+cnt+slot-prefix + pack all weights
  k_init<<<64,256,0,stream>>>(W1_rel, W1_root, W5_rel, W5_root, Wg,
                              wc1b, wc5b, wgb, g, slot);

  // fused CSR scatter + conv1 MFMA (independent halves, one dispatch)
  k_c1_fill<<<FILL_BLOCKS + (N_NODES+63)/64,256,0,stream>>>(
      src, dst, cnt, slot, x, wc1b, b1, xr_b, rootb);

  // FUSED conv1-agg + GAT transform (h1 lives in LDS only)
  k_agg3<<<(N_NODES+63)/64,256,0,stream>>>(cnt, slot, xr_b, rootb, wgb,
      att_src, att_dst, xlb_hm, a_s_hm, a_d_hm);

  // GAT softmax-agg
  k_gat_node<<<((N_NODES+15)/16)*HEADS,256,0,stream>>>(cnt, slot,
      xlb_hm, a_s_hm, a_d_hm, bg, h2b_hm);

  // conv5 (MFMA, head-major A) + pool-side agg (atomics -> g)
  conv5_mfma<<<(N_NODES+63)/64,256,0,stream>>>(h2b_hm, wc5b, b5, xr_b, rootb);
  k_aggb<<<N_NODES,256,0,stream>>>(cnt, slot, xr_b, rootb, batch, g);

  // head
  k_head<<<1,256,0,stream>>>(g, W_fc1, b_fc1, W_fc2, b_fc2, out);
}